// Round 1
// baseline (27551.257 us; speedup 1.0000x reference)
//
#include <hip/hip_runtime.h>
#include <math.h>

namespace {

constexpr int kB  = 2;
constexpr int kS  = 1024;
constexpr int kD  = 1000;
constexpr int kE  = 20;
constexpr int kHD = 50;
constexpr int kF  = 2048;
constexpr int kQKV = 3 * kHD;   // 150

// ---------------------------------------------------------------- elementwise
__global__ __launch_bounds__(256) void zero_kernel(float* __restrict__ p, int n) {
    int i = blockIdx.x * 256 + threadIdx.x;
    if (i < n) p[i] = 0.0f;
}

__global__ __launch_bounds__(256) void gelu_kernel(float* __restrict__ p, int n) {
    int i = blockIdx.x * 256 + threadIdx.x;
    if (i < n) {
        float x = p[i];
        p[i] = 0.5f * x * (1.0f + erff(x * 0.70710678118654752440f));
    }
}

// seg[b][r][d] = src[b][(st+r) mod S][d]
__global__ __launch_bounds__(256) void gather_kernel(const float* __restrict__ src,
                                                     float* __restrict__ dst,
                                                     int st, int sseg) {
    int i = blockIdx.x * 256 + threadIdx.x;
    int tot = kB * sseg * kD;
    if (i >= tot) return;
    int d  = i % kD;
    int tr = i / kD;
    int r  = tr % sseg;
    int b  = tr / sseg;
    int srow = st + r;
    if (srow >= kS) srow -= kS;
    dst[i] = src[(b * kS + srow) * kD + d];
}

// dst[b][(st+r) mod S][d] += src[b][r][d]   (kernels serialized on stream -> plain add ok)
__global__ __launch_bounds__(256) void scatter_add_kernel(const float* __restrict__ src,
                                                          float* __restrict__ dst,
                                                          int st, int sseg) {
    int i = blockIdx.x * 256 + threadIdx.x;
    int tot = kB * sseg * kD;
    if (i >= tot) return;
    int d  = i % kD;
    int tr = i / kD;
    int r  = tr % sseg;
    int b  = tr / sseg;
    int drow = st + r;
    if (drow >= kS) drow -= kS;
    dst[(b * kS + drow) * kD + d] += src[i];
}

// cur = xnew / counts   (counts formula inlined for s=1024 schedule)
__global__ __launch_bounds__(256) void finalize_kernel(const float* __restrict__ xn,
                                                       float* __restrict__ cur) {
    int i = blockIdx.x * 256 + threadIdx.x;
    const int tot = kB * kS * kD;
    if (i >= tot) return;
    int r = (i / kD) % kS;
    float cnt = 0.0f;
    cnt += (r < 460) ? 1.0f : 0.0f;                // seg0 [0,460)
    cnt += (r >= 256 && r < 665) ? 1.0f : 0.0f;    // seg1 [256,665)
    cnt += (r >= 460 && r < 870) ? 1.0f : 0.0f;    // seg2 [460,870)
    cnt += (r >= 665) ? 1.0f : 0.0f;               // seg3 [665,1024)
    cnt += (r < 51) ? 1.0f : 0.0f;                 // wrap [0,51)
    cnt = fmaxf(cnt, 1.0f);
    cur[i] = xn[i] / cnt;
}

// ---------------------------------------------------------------- GEMM
// C[M,N] = A[M,K] @ W[K,N] + bias[N], batched over blockIdx.z via strides.
// 64x64 tile, BK=16, 256 threads, 4x4 micro-tile per thread. fp32.
__global__ __launch_bounds__(256) void gemm_kernel(
    const float* __restrict__ A, const float* __restrict__ W,
    const float* __restrict__ bias, float* __restrict__ C,
    int M, int N, int K,
    long long strideW, long long strideC, long long strideBias)
{
    constexpr int BM = 64, BN = 64, BK = 16;
    W    += (long long)blockIdx.z * strideW;
    C    += (long long)blockIdx.z * strideC;
    bias += (long long)blockIdx.z * strideBias;

    __shared__ float As[BK][BM + 1];
    __shared__ float Bs[BK][BN + 1];

    const int tx = threadIdx.x % 16;       // col group
    const int ty = threadIdx.x / 16;       // row group
    const int row0 = blockIdx.y * BM;
    const int col0 = blockIdx.x * BN;

    float acc[4][4] = {};

    for (int k0 = 0; k0 < K; k0 += BK) {
        // A tile: 64 rows x 16 k
        #pragma unroll
        for (int i = 0; i < 4; i++) {
            int idx = threadIdx.x + i * 256;
            int r = idx / BK, c = idx % BK;
            int gr = row0 + r, gc = k0 + c;
            As[c][r] = (gr < M && gc < K) ? A[(long long)gr * K + gc] : 0.0f;
        }
        // W tile: 16 k x 64 cols
        #pragma unroll
        for (int i = 0; i < 4; i++) {
            int idx = threadIdx.x + i * 256;
            int r = idx / BN, c = idx % BN;
            int gr = k0 + r, gc = col0 + c;
            Bs[r][c] = (gr < K && gc < N) ? W[(long long)gr * N + gc] : 0.0f;
        }
        __syncthreads();
        #pragma unroll
        for (int kk = 0; kk < BK; kk++) {
            float a[4], b[4];
            #pragma unroll
            for (int i = 0; i < 4; i++) a[i] = As[kk][ty * 4 + i];
            #pragma unroll
            for (int j = 0; j < 4; j++) b[j] = Bs[kk][tx * 4 + j];
            #pragma unroll
            for (int i = 0; i < 4; i++)
                #pragma unroll
                for (int j = 0; j < 4; j++)
                    acc[i][j] = fmaf(a[i], b[j], acc[i][j]);
        }
        __syncthreads();
    }

    #pragma unroll
    for (int i = 0; i < 4; i++) {
        int gr = row0 + ty * 4 + i;
        if (gr >= M) continue;
        #pragma unroll
        for (int j = 0; j < 4; j++) {
            int gc = col0 + tx * 4 + j;
            if (gc >= N) continue;
            C[(long long)gr * N + gc] = acc[i][j] + bias[gc];
        }
    }
}

// ---------------------------------------------------------------- routing
// One wave per token: logits = x @ rw + rb (E=20), softmax over E.
__global__ __launch_bounds__(256) void routing_kernel(
    const float* __restrict__ X, const float* __restrict__ RW,
    const float* __restrict__ RB, float* __restrict__ R, int T)
{
    int wave = (blockIdx.x * 256 + threadIdx.x) / 64;
    int lane = threadIdx.x & 63;
    if (wave >= T) return;
    const float* x = X + (long long)wave * kD;

    float xr[16];
    #pragma unroll
    for (int i = 0; i < 16; i++) {
        int d = lane + 64 * i;
        xr[i] = (d < kD) ? x[d] : 0.0f;
    }
    float r[kE];
    #pragma unroll
    for (int e = 0; e < kE; e++) {
        float acc = 0.0f;
        #pragma unroll
        for (int i = 0; i < 16; i++) {
            int d = lane + 64 * i;
            if (d < kD) acc = fmaf(xr[i], RW[d * kE + e], acc);
        }
        #pragma unroll
        for (int off = 32; off > 0; off >>= 1) acc += __shfl_xor(acc, off, 64);
        r[e] = acc + RB[e];
    }
    float m = r[0];
    #pragma unroll
    for (int e = 1; e < kE; e++) m = fmaxf(m, r[e]);
    float sum = 0.0f;
    #pragma unroll
    for (int e = 0; e < kE; e++) { r[e] = expf(r[e] - m); sum += r[e]; }
    float inv = 1.0f / sum;
    float mine = 0.0f;
    #pragma unroll
    for (int e = 0; e < kE; e++) if (lane == e) mine = r[e] * inv;  // static-index select
    if (lane < kE) R[(long long)wave * kE + lane] = mine;
}

// ---------------------------------------------------------------- attention
// One block per (query row, expert, batch). QKV layout [E][T][150], T = kB*s.
// Epilogue fuses softmax normalization, routing scale, and head-combine store.
__global__ __launch_bounds__(256) void attn_kernel(
    const float* __restrict__ QKV, const float* __restrict__ R,
    float* __restrict__ O, int s)
{
    const int row = blockIdx.x, e = blockIdx.y, b = blockIdx.z;
    const int T = kB * s;
    const int t = b * s + row;
    const float* base = QKV + (long long)e * T * kQKV;

    __shared__ float qs[kHD];
    __shared__ float sc[kS];
    __shared__ float red[4];
    __shared__ float outp[5][kHD];

    const int tid = threadIdx.x;
    if (tid < kHD) qs[tid] = base[(long long)t * kQKV + tid];
    __syncthreads();

    // scores + local max
    float lmax = -1e30f;
    for (int j = tid; j < s; j += 256) {
        const float* kp = base + (long long)(b * s + j) * kQKV + kHD;
        float acc = 0.0f;
        #pragma unroll
        for (int h = 0; h < kHD; h++) acc = fmaf(qs[h], kp[h], acc);
        acc *= 0.14142135623730950488f;   // 50^-0.5
        sc[j] = acc;
        lmax = fmaxf(lmax, acc);
    }
    #pragma unroll
    for (int off = 32; off > 0; off >>= 1) lmax = fmaxf(lmax, __shfl_xor(lmax, off, 64));
    if ((tid & 63) == 0) red[tid >> 6] = lmax;
    __syncthreads();
    float bmax = fmaxf(fmaxf(red[0], red[1]), fmaxf(red[2], red[3]));
    __syncthreads();   // all read red before reuse

    // exp + sum (unnormalized probs left in sc[])
    float lsum = 0.0f;
    for (int j = tid; j < s; j += 256) {
        float p = expf(sc[j] - bmax);
        sc[j] = p;
        lsum += p;
    }
    #pragma unroll
    for (int off = 32; off > 0; off >>= 1) lsum += __shfl_xor(lsum, off, 64);
    if ((tid & 63) == 0) red[tid >> 6] = lsum;
    __syncthreads();
    float bsum = red[0] + red[1] + red[2] + red[3];
    float rscale = R[(long long)t * kE + e] / bsum;  // softmax norm * routing weight

    // out[h] = sum_j p[j] * v[j][h]; 5 groups of 50 threads
    const int g = tid / kHD, h = tid % kHD;
    if (g < 5) {
        float acc = 0.0f;
        for (int j = g; j < s; j += 5) {
            acc = fmaf(sc[j], base[(long long)(b * s + j) * kQKV + 2 * kHD + h], acc);
        }
        outp[g][h] = acc;
    }
    __syncthreads();
    if (tid < kHD) {
        float v = (outp[0][tid] + outp[1][tid] + outp[2][tid] + outp[3][tid] + outp[4][tid]) * rscale;
        O[(long long)t * kD + e * kHD + tid] = v;   // combined d = e*HD + h
    }
}

// ---------------------------------------------------------------- layernorm
// Y = LN(Xres + A) * G + Bb, two-pass mean/var, one block per token.
__global__ __launch_bounds__(256) void ln_kernel(
    const float* __restrict__ Xres, const float* __restrict__ A,
    const float* __restrict__ G, const float* __restrict__ Bb,
    float* __restrict__ Y)
{
    const int t = blockIdx.x;
    const float* x = Xres + (long long)t * kD;
    const float* a = A + (long long)t * kD;
    __shared__ float buf[kD];
    __shared__ float red[4];
    const int tid = threadIdx.x;

    float lsum = 0.0f;
    for (int d = tid; d < kD; d += 256) {
        float v = x[d] + a[d];
        buf[d] = v;
        lsum += v;
    }
    #pragma unroll
    for (int off = 32; off > 0; off >>= 1) lsum += __shfl_xor(lsum, off, 64);
    if ((tid & 63) == 0) red[tid >> 6] = lsum;
    __syncthreads();
    float mean = (red[0] + red[1] + red[2] + red[3]) * (1.0f / kD);

    float lv = 0.0f;
    for (int d = tid; d < kD; d += 256) {
        float u = buf[d] - mean;
        lv = fmaf(u, u, lv);
    }
    #pragma unroll
    for (int off = 32; off > 0; off >>= 1) lv += __shfl_xor(lv, off, 64);
    __syncthreads();   // everyone done reading red (mean)
    if ((tid & 63) == 0) red[tid >> 6] = lv;
    __syncthreads();
    float var = (red[0] + red[1] + red[2] + red[3]) * (1.0f / kD);
    float inv = rsqrtf(var + 1e-5f);

    for (int d = tid; d < kD; d += 256)
        Y[(long long)t * kD + d] = (buf[d] - mean) * inv * G[d] + Bb[d];
}

// ---------------------------------------------------------------- host side
struct Params {
    const float *expert_w, *expert_b, *router_w, *router_b, *out_w, *out_b;
    const float *ln1_g, *ln1_b, *ff_w1, *ff_b1, *ff_w2, *ff_b2, *ln2_g, *ln2_b;
};

void run_block(const float* xin, float* xout, int s, int li, const Params& P,
               float* routing, float* qkv, float* attn_comb, float* a_out,
               float* y1, float* h, float* f, hipStream_t stream)
{
    const int T = kB * s;

    // routing softmax
    routing_kernel<<<(T + 3) / 4, 256, 0, stream>>>(
        xin, P.router_w + (long long)li * kD * kE, P.router_b + li * kE, routing, T);

    // QKV: batched over experts
    {
        dim3 grid((kQKV + 63) / 64, (T + 63) / 64, kE);
        gemm_kernel<<<grid, 256, 0, stream>>>(
            xin, P.expert_w + (long long)li * kE * kD * kQKV,
            P.expert_b + (long long)li * kE * kQKV, qkv,
            T, kQKV, kD,
            (long long)kD * kQKV, (long long)T * kQKV, (long long)kQKV);
    }

    // attention (+routing scale, head combine)
    {
        dim3 grid(s, kE, kB);
        attn_kernel<<<grid, 256, 0, stream>>>(qkv, routing, attn_comb, s);
    }

    // out projection
    {
        dim3 grid((kD + 63) / 64, (T + 63) / 64, 1);
        gemm_kernel<<<grid, 256, 0, stream>>>(
            attn_comb, P.out_w + (long long)li * kD * kD, P.out_b + li * kD, a_out,
            T, kD, kD, 0, 0, 0);
    }

    // LN1(x + a)
    ln_kernel<<<T, 256, 0, stream>>>(xin, a_out, P.ln1_g + li * kD, P.ln1_b + li * kD, y1);

    // FFN1 + GELU
    {
        dim3 grid((kF + 63) / 64, (T + 63) / 64, 1);
        gemm_kernel<<<grid, 256, 0, stream>>>(
            y1, P.ff_w1 + (long long)li * kD * kF, P.ff_b1 + li * kF, h,
            T, kF, kD, 0, 0, 0);
    }
    gelu_kernel<<<(T * kF + 255) / 256, 256, 0, stream>>>(h, T * kF);

    // FFN2
    {
        dim3 grid((kD + 63) / 64, (T + 63) / 64, 1);
        gemm_kernel<<<grid, 256, 0, stream>>>(
            h, P.ff_w2 + (long long)li * kF * kD, P.ff_b2 + li * kD, f,
            T, kD, kF, 0, 0, 0);
    }

    // LN2(y1 + f)
    ln_kernel<<<T, 256, 0, stream>>>(y1, f, P.ln2_g + li * kD, P.ln2_b + li * kD, xout);
}

} // namespace

extern "C" void kernel_launch(void* const* d_in, const int* in_sizes, int n_in,
                              void* d_out, int out_size, void* d_ws, size_t ws_size,
                              hipStream_t stream)
{
    const float* x = (const float*)d_in[0];
    Params P;
    P.expert_w = (const float*)d_in[1];
    P.expert_b = (const float*)d_in[2];
    P.router_w = (const float*)d_in[3];
    P.router_b = (const float*)d_in[4];
    P.out_w    = (const float*)d_in[5];
    P.out_b    = (const float*)d_in[6];
    P.ln1_g    = (const float*)d_in[7];
    P.ln1_b    = (const float*)d_in[8];
    P.ff_w1    = (const float*)d_in[9];
    P.ff_b1    = (const float*)d_in[10];
    P.ff_w2    = (const float*)d_in[11];
    P.ff_b2    = (const float*)d_in[12];
    P.ln2_g    = (const float*)d_in[13];
    P.ln2_b    = (const float*)d_in[14];

    const int TD = kB * kS * kD;               // 2,048,000
    float* ws = (float*)d_ws;
    float* cur       = ws;  ws += TD;
    float* xnew      = ws;  ws += TD;
    float* seg       = ws;  ws += TD;
    float* routing   = ws;  ws += kB * kS * kE;
    float* qkv       = ws;  ws += kE * kB * kS * kQKV;   // 6,144,000
    float* attn_comb = ws;  ws += TD;
    float* a_out     = ws;  ws += TD;
    float* y1        = ws;  ws += TD;
    float* h         = ws;  ws += kB * kS * kF;          // 4,194,304
    float* f         = ws;  ws += TD;
    float* bout      = (float*)d_out;   // reuse output buffer as per-segment block output

    // block 0 (full sequence) from pristine input
    run_block(x, cur, kS, 0, P, routing, qkv, attn_comb, a_out, y1, h, f, stream);

    const int st_arr[4]  = {0, 256, 460, 665};
    const int len_arr[4] = {460, 409, 410, 410};   // seg3 = 359 tail + 51 wrap

    for (int c = 0; c < 3; c++) {
        zero_kernel<<<(TD + 255) / 256, 256, 0, stream>>>(xnew, TD);
        for (int j = 0; j < 4; j++) {
            const int st = st_arr[j], sl = len_arr[j];
            const int li = 1 + 4 * c + j;
            const int n = kB * sl * kD;
            gather_kernel<<<(n + 255) / 256, 256, 0, stream>>>(cur, seg, st, sl);
            run_block(seg, bout, sl, li, P, routing, qkv, attn_comb, a_out, y1, h, f, stream);
            scatter_add_kernel<<<(n + 255) / 256, 256, 0, stream>>>(bout, xnew, st, sl);
        }
        finalize_kernel<<<(TD + 255) / 256, 256, 0, stream>>>(xnew, cur);
    }

    // final block (full sequence) -> d_out
    run_block(cur, (float*)d_out, kS, 13, P, routing, qkv, attn_comb, a_out, y1, h, f, stream);
}

// Round 2
// 19530.031 us; speedup vs baseline: 1.4107x; 1.4107x over previous
//
#include <hip/hip_runtime.h>
#include <math.h>

namespace {

constexpr int kB  = 2;
constexpr int kS  = 1024;
constexpr int kD  = 1000;
constexpr int kE  = 20;
constexpr int kHD = 50;
constexpr int kF  = 2048;
constexpr int kQKV = 3 * kHD;   // 150

// ---------------------------------------------------------------- elementwise
__global__ __launch_bounds__(256) void zero_kernel(float* __restrict__ p, int n) {
    int i = blockIdx.x * 256 + threadIdx.x;
    if (i < n) p[i] = 0.0f;
}

__global__ __launch_bounds__(256) void gelu_kernel(float* __restrict__ p, int n) {
    int i = blockIdx.x * 256 + threadIdx.x;
    if (i < n) {
        float x = p[i];
        p[i] = 0.5f * x * (1.0f + erff(x * 0.70710678118654752440f));
    }
}

// seg[b][r][d] = src[b][(st+r) mod S][d]
__global__ __launch_bounds__(256) void gather_kernel(const float* __restrict__ src,
                                                     float* __restrict__ dst,
                                                     int st, int sseg) {
    int i = blockIdx.x * 256 + threadIdx.x;
    int tot = kB * sseg * kD;
    if (i >= tot) return;
    int d  = i % kD;
    int tr = i / kD;
    int r  = tr % sseg;
    int b  = tr / sseg;
    int srow = st + r;
    if (srow >= kS) srow -= kS;
    dst[i] = src[(b * kS + srow) * kD + d];
}

// dst[b][(st+r) mod S][d] += src[b][r][d]
__global__ __launch_bounds__(256) void scatter_add_kernel(const float* __restrict__ src,
                                                          float* __restrict__ dst,
                                                          int st, int sseg) {
    int i = blockIdx.x * 256 + threadIdx.x;
    int tot = kB * sseg * kD;
    if (i >= tot) return;
    int d  = i % kD;
    int tr = i / kD;
    int r  = tr % sseg;
    int b  = tr / sseg;
    int drow = st + r;
    if (drow >= kS) drow -= kS;
    dst[(b * kS + drow) * kD + d] += src[i];
}

// cur = xnew / counts
__global__ __launch_bounds__(256) void finalize_kernel(const float* __restrict__ xn,
                                                       float* __restrict__ cur) {
    int i = blockIdx.x * 256 + threadIdx.x;
    const int tot = kB * kS * kD;
    if (i >= tot) return;
    int r = (i / kD) % kS;
    float cnt = 0.0f;
    cnt += (r < 460) ? 1.0f : 0.0f;
    cnt += (r >= 256 && r < 665) ? 1.0f : 0.0f;
    cnt += (r >= 460 && r < 870) ? 1.0f : 0.0f;
    cnt += (r >= 665) ? 1.0f : 0.0f;
    cnt += (r < 51) ? 1.0f : 0.0f;
    cnt = fmaxf(cnt, 1.0f);
    cur[i] = xn[i] / cnt;
}

// ---------------------------------------------------------------- GEMM (fp32)
__global__ __launch_bounds__(256) void gemm_kernel(
    const float* __restrict__ A, const float* __restrict__ W,
    const float* __restrict__ bias, float* __restrict__ C,
    int M, int N, int K,
    long long strideW, long long strideC, long long strideBias)
{
    constexpr int BM = 64, BN = 64, BK = 16;
    W    += (long long)blockIdx.z * strideW;
    C    += (long long)blockIdx.z * strideC;
    bias += (long long)blockIdx.z * strideBias;

    __shared__ float As[BK][BM + 1];
    __shared__ float Bs[BK][BN + 1];

    const int tx = threadIdx.x % 16;
    const int ty = threadIdx.x / 16;
    const int row0 = blockIdx.y * BM;
    const int col0 = blockIdx.x * BN;

    float acc[4][4] = {};

    for (int k0 = 0; k0 < K; k0 += BK) {
        #pragma unroll
        for (int i = 0; i < 4; i++) {
            int idx = threadIdx.x + i * 256;
            int r = idx / BK, c = idx % BK;
            int gr = row0 + r, gc = k0 + c;
            As[c][r] = (gr < M && gc < K) ? A[(long long)gr * K + gc] : 0.0f;
        }
        #pragma unroll
        for (int i = 0; i < 4; i++) {
            int idx = threadIdx.x + i * 256;
            int r = idx / BN, c = idx % BN;
            int gr = k0 + r, gc = col0 + c;
            Bs[r][c] = (gr < K && gc < N) ? W[(long long)gr * N + gc] : 0.0f;
        }
        __syncthreads();
        #pragma unroll
        for (int kk = 0; kk < BK; kk++) {
            float a[4], b[4];
            #pragma unroll
            for (int i = 0; i < 4; i++) a[i] = As[kk][ty * 4 + i];
            #pragma unroll
            for (int j = 0; j < 4; j++) b[j] = Bs[kk][tx * 4 + j];
            #pragma unroll
            for (int i = 0; i < 4; i++)
                #pragma unroll
                for (int j = 0; j < 4; j++)
                    acc[i][j] = fmaf(a[i], b[j], acc[i][j]);
        }
        __syncthreads();
    }

    #pragma unroll
    for (int i = 0; i < 4; i++) {
        int gr = row0 + ty * 4 + i;
        if (gr >= M) continue;
        #pragma unroll
        for (int j = 0; j < 4; j++) {
            int gc = col0 + tx * 4 + j;
            if (gc >= N) continue;
            C[(long long)gr * N + gc] = acc[i][j] + bias[gc];
        }
    }
}

// ---------------------------------------------------------------- routing
__global__ __launch_bounds__(256) void routing_kernel(
    const float* __restrict__ X, const float* __restrict__ RW,
    const float* __restrict__ RB, float* __restrict__ R, int T)
{
    int wave = (blockIdx.x * 256 + threadIdx.x) / 64;
    int lane = threadIdx.x & 63;
    if (wave >= T) return;
    const float* x = X + (long long)wave * kD;

    float xr[16];
    #pragma unroll
    for (int i = 0; i < 16; i++) {
        int d = lane + 64 * i;
        xr[i] = (d < kD) ? x[d] : 0.0f;
    }
    float r[kE];
    #pragma unroll
    for (int e = 0; e < kE; e++) {
        float acc = 0.0f;
        #pragma unroll
        for (int i = 0; i < 16; i++) {
            int d = lane + 64 * i;
            if (d < kD) acc = fmaf(xr[i], RW[d * kE + e], acc);
        }
        #pragma unroll
        for (int off = 32; off > 0; off >>= 1) acc += __shfl_xor(acc, off, 64);
        r[e] = acc + RB[e];
    }
    float m = r[0];
    #pragma unroll
    for (int e = 1; e < kE; e++) m = fmaxf(m, r[e]);
    float sum = 0.0f;
    #pragma unroll
    for (int e = 0; e < kE; e++) { r[e] = expf(r[e] - m); sum += r[e]; }
    float inv = 1.0f / sum;
    float mine = 0.0f;
    #pragma unroll
    for (int e = 0; e < kE; e++) if (lane == e) mine = r[e] * inv;
    if (lane < kE) R[(long long)wave * kE + lane] = mine;
}

// ---------------------------------------------------------------- attention
// Flash-style tiled attention. Block = (64-query tile, expert e, batch b).
// QKV layout [E][T][150] with T = kB*s; rows of this (e,b) start at b*s.
// Online softmax: m/l/alpha per row in LDS; PV accumulated in registers
// (4x4 micro-tile per thread); epilogue fuses 1/l, routing weight, and
// head-combine store (d = e*50 + h), staged through LDS for coalescing.
__global__ __launch_bounds__(256) void attn_kernel(
    const float* __restrict__ QKV, const float* __restrict__ R,
    float* __restrict__ O, int s)
{
    const int q0 = blockIdx.x * 64;
    const int e  = blockIdx.y;
    const int b  = blockIdx.z;
    const int T  = kB * s;
    const float* base = QKV + ((long long)e * T + (long long)b * s) * kQKV;

    // pads: 51 -> 4*51=204 % 32 = 12-word lane stride, <=2 addrs/bank (free)
    __shared__ float Qs[64][51];
    __shared__ float Ks[64][51];
    __shared__ float Vs[64][51];
    __shared__ float Sb[64][65];
    __shared__ float mrow[64], lrow[64], arow[64];

    const int tid = threadIdx.x;
    const int tx = tid & 15, ty = tid >> 4;

    // Q tile (coalesced: consecutive threads -> consecutive h)
    for (int idx = tid; idx < 64 * kHD; idx += 256) {
        int r = idx / kHD, h = idx % kHD;
        int q = q0 + r;
        Qs[r][h] = (q < s) ? base[(long long)q * kQKV + h] : 0.0f;
    }
    if (tid < 64) { mrow[tid] = -1e30f; lrow[tid] = 0.0f; }

    float o[4][4] = {};   // rows ty*4+i, cols tx*4+j (col<50 valid)

    for (int k0 = 0; k0 < s; k0 += 64) {
        const int kn = min(64, s - k0);
        __syncthreads();   // prev-tile P/V reads done before overwrite
        for (int idx = tid; idx < 64 * kHD; idx += 256) {
            int r = idx / kHD, h = idx % kHD;
            const float* row = base + (long long)(k0 + r) * kQKV;
            bool ok = (r < kn);
            Ks[r][h] = ok ? row[kHD + h] : 0.0f;
            Vs[r][h] = ok ? row[2 * kHD + h] : 0.0f;
        }
        __syncthreads();

        // scores 64x64, 4x4 per thread, K-dim = 50
        float sacc[4][4] = {};
        for (int kk = 0; kk < kHD; kk++) {
            float a[4], bb[4];
            #pragma unroll
            for (int i = 0; i < 4; i++) a[i] = Qs[ty * 4 + i][kk];
            #pragma unroll
            for (int j = 0; j < 4; j++) bb[j] = Ks[tx * 4 + j][kk];
            #pragma unroll
            for (int i = 0; i < 4; i++)
                #pragma unroll
                for (int j = 0; j < 4; j++)
                    sacc[i][j] = fmaf(a[i], bb[j], sacc[i][j]);
        }
        #pragma unroll
        for (int i = 0; i < 4; i++)
            #pragma unroll
            for (int j = 0; j < 4; j++)
                Sb[ty * 4 + i][tx * 4 + j] = sacc[i][j] * 0.14142135623730950488f;
        __syncthreads();

        // online-softmax row update (threads 0..63, one row each)
        if (tid < 64) {
            float m_old = mrow[tid];
            float tmax = -1e30f;
            for (int j = 0; j < kn; j++) tmax = fmaxf(tmax, Sb[tid][j]);
            float m_new = fmaxf(m_old, tmax);
            float alpha = __expf(m_old - m_new);
            float rs = 0.0f;
            for (int j = 0; j < 64; j++) {
                float p = (j < kn) ? __expf(Sb[tid][j] - m_new) : 0.0f;
                Sb[tid][j] = p;
                rs += p;
            }
            mrow[tid] = m_new;
            lrow[tid] = lrow[tid] * alpha + rs;
            arow[tid] = alpha;
        }
        __syncthreads();

        // o = o*alpha + P*V   (P in Sb, V in Vs)
        float al[4];
        #pragma unroll
        for (int i = 0; i < 4; i++) al[i] = arow[ty * 4 + i];
        #pragma unroll
        for (int i = 0; i < 4; i++)
            #pragma unroll
            for (int j = 0; j < 4; j++)
                o[i][j] *= al[i];
        for (int j = 0; j < 64; j++) {
            float p[4], v[4];
            #pragma unroll
            for (int i = 0; i < 4; i++) p[i] = Sb[ty * 4 + i][j];
            #pragma unroll
            for (int c = 0; c < 4; c++) v[c] = Vs[j][tx * 4 + c];
            #pragma unroll
            for (int i = 0; i < 4; i++)
                #pragma unroll
                for (int c = 0; c < 4; c++)
                    o[i][c] = fmaf(p[i], v[c], o[i][c]);
        }
    }

    // stage to LDS, then coalesced store with 1/l * routing weight
    __syncthreads();
    #pragma unroll
    for (int i = 0; i < 4; i++)
        #pragma unroll
        for (int j = 0; j < 4; j++) {
            int h = tx * 4 + j;
            if (h < kHD) Sb[ty * 4 + i][h] = o[i][j];
        }
    __syncthreads();
    for (int idx = tid; idx < 64 * kHD; idx += 256) {
        int r = idx / kHD, h = idx % kHD;
        int q = q0 + r;
        if (q < s) {
            long long t = (long long)b * s + q;
            float scale = R[t * kE + e] / lrow[r];
            O[t * kD + e * kHD + h] = Sb[r][h] * scale;
        }
    }
}

// ---------------------------------------------------------------- layernorm
__global__ __launch_bounds__(256) void ln_kernel(
    const float* __restrict__ Xres, const float* __restrict__ A,
    const float* __restrict__ G, const float* __restrict__ Bb,
    float* __restrict__ Y)
{
    const int t = blockIdx.x;
    const float* x = Xres + (long long)t * kD;
    const float* a = A + (long long)t * kD;
    __shared__ float buf[kD];
    __shared__ float red[4];
    const int tid = threadIdx.x;

    float lsum = 0.0f;
    for (int d = tid; d < kD; d += 256) {
        float v = x[d] + a[d];
        buf[d] = v;
        lsum += v;
    }
    #pragma unroll
    for (int off = 32; off > 0; off >>= 1) lsum += __shfl_xor(lsum, off, 64);
    if ((tid & 63) == 0) red[tid >> 6] = lsum;
    __syncthreads();
    float mean = (red[0] + red[1] + red[2] + red[3]) * (1.0f / kD);

    float lv = 0.0f;
    for (int d = tid; d < kD; d += 256) {
        float u = buf[d] - mean;
        lv = fmaf(u, u, lv);
    }
    #pragma unroll
    for (int off = 32; off > 0; off >>= 1) lv += __shfl_xor(lv, off, 64);
    __syncthreads();
    if ((tid & 63) == 0) red[tid >> 6] = lv;
    __syncthreads();
    float var = (red[0] + red[1] + red[2] + red[3]) * (1.0f / kD);
    float inv = rsqrtf(var + 1e-5f);

    for (int d = tid; d < kD; d += 256)
        Y[(long long)t * kD + d] = (buf[d] - mean) * inv * G[d] + Bb[d];
}

// ---------------------------------------------------------------- host side
struct Params {
    const float *expert_w, *expert_b, *router_w, *router_b, *out_w, *out_b;
    const float *ln1_g, *ln1_b, *ff_w1, *ff_b1, *ff_w2, *ff_b2, *ln2_g, *ln2_b;
};

void run_block(const float* xin, float* xout, int s, int li, const Params& P,
               float* routing, float* qkv, float* attn_comb, float* a_out,
               float* y1, float* h, float* f, hipStream_t stream)
{
    const int T = kB * s;

    routing_kernel<<<(T + 3) / 4, 256, 0, stream>>>(
        xin, P.router_w + (long long)li * kD * kE, P.router_b + li * kE, routing, T);

    {
        dim3 grid((kQKV + 63) / 64, (T + 63) / 64, kE);
        gemm_kernel<<<grid, 256, 0, stream>>>(
            xin, P.expert_w + (long long)li * kE * kD * kQKV,
            P.expert_b + (long long)li * kE * kQKV, qkv,
            T, kQKV, kD,
            (long long)kD * kQKV, (long long)T * kQKV, (long long)kQKV);
    }

    {
        dim3 grid((s + 63) / 64, kE, kB);
        attn_kernel<<<grid, 256, 0, stream>>>(qkv, routing, attn_comb, s);
    }

    {
        dim3 grid((kD + 63) / 64, (T + 63) / 64, 1);
        gemm_kernel<<<grid, 256, 0, stream>>>(
            attn_comb, P.out_w + (long long)li * kD * kD, P.out_b + li * kD, a_out,
            T, kD, kD, 0, 0, 0);
    }

    ln_kernel<<<T, 256, 0, stream>>>(xin, a_out, P.ln1_g + li * kD, P.ln1_b + li * kD, y1);

    {
        dim3 grid((kF + 63) / 64, (T + 63) / 64, 1);
        gemm_kernel<<<grid, 256, 0, stream>>>(
            y1, P.ff_w1 + (long long)li * kD * kF, P.ff_b1 + li * kF, h,
            T, kF, kD, 0, 0, 0);
    }
    gelu_kernel<<<(T * kF + 255) / 256, 256, 0, stream>>>(h, T * kF);

    {
        dim3 grid((kD + 63) / 64, (T + 63) / 64, 1);
        gemm_kernel<<<grid, 256, 0, stream>>>(
            h, P.ff_w2 + (long long)li * kF * kD, P.ff_b2 + li * kD, f,
            T, kD, kF, 0, 0, 0);
    }

    ln_kernel<<<T, 256, 0, stream>>>(y1, f, P.ln2_g + li * kD, P.ln2_b + li * kD, xout);
}

} // namespace

extern "C" void kernel_launch(void* const* d_in, const int* in_sizes, int n_in,
                              void* d_out, int out_size, void* d_ws, size_t ws_size,
                              hipStream_t stream)
{
    const float* x = (const float*)d_in[0];
    Params P;
    P.expert_w = (const float*)d_in[1];
    P.expert_b = (const float*)d_in[2];
    P.router_w = (const float*)d_in[3];
    P.router_b = (const float*)d_in[4];
    P.out_w    = (const float*)d_in[5];
    P.out_b    = (const float*)d_in[6];
    P.ln1_g    = (const float*)d_in[7];
    P.ln1_b    = (const float*)d_in[8];
    P.ff_w1    = (const float*)d_in[9];
    P.ff_b1    = (const float*)d_in[10];
    P.ff_w2    = (const float*)d_in[11];
    P.ff_b2    = (const float*)d_in[12];
    P.ln2_g    = (const float*)d_in[13];
    P.ln2_b    = (const float*)d_in[14];

    const int TD = kB * kS * kD;
    float* ws = (float*)d_ws;
    float* cur       = ws;  ws += TD;
    float* xnew      = ws;  ws += TD;
    float* seg       = ws;  ws += TD;
    float* routing   = ws;  ws += kB * kS * kE;
    float* qkv       = ws;  ws += kE * kB * kS * kQKV;
    float* attn_comb = ws;  ws += TD;
    float* a_out     = ws;  ws += TD;
    float* y1        = ws;  ws += TD;
    float* h         = ws;  ws += kB * kS * kF;
    float* f         = ws;  ws += TD;
    float* bout      = (float*)d_out;

    run_block(x, cur, kS, 0, P, routing, qkv, attn_comb, a_out, y1, h, f, stream);

    const int st_arr[4]  = {0, 256, 460, 665};
    const int len_arr[4] = {460, 409, 410, 410};

    for (int c = 0; c < 3; c++) {
        zero_kernel<<<(TD + 255) / 256, 256, 0, stream>>>(xnew, TD);
        for (int j = 0; j < 4; j++) {
            const int st = st_arr[j], sl = len_arr[j];
            const int li = 1 + 4 * c + j;
            const int n = kB * sl * kD;
            gather_kernel<<<(n + 255) / 256, 256, 0, stream>>>(cur, seg, st, sl);
            run_block(seg, bout, sl, li, P, routing, qkv, attn_comb, a_out, y1, h, f, stream);
            scatter_add_kernel<<<(n + 255) / 256, 256, 0, stream>>>(bout, xnew, st, sl);
        }
        finalize_kernel<<<(TD + 255) / 256, 256, 0, stream>>>(xnew, cur);
    }

    run_block(cur, (float*)d_out, kS, 13, P, routing, qkv, attn_comb, a_out, y1, h, f, stream);
}